// Round 3
// baseline (147118.750 us; speedup 1.0000x reference)
//
#include <hip/hip_runtime.h>

#define NEGV -1000000000.0f

struct Params {
  const float *memory, *dec_in; const int *memlen;
  const float *w1, *w2;
  const float *awih, *awhh, *abih, *abhh;
  const float *qw, *mw, *vw, *lcw, *ldw;
  const float *dwih, *dwhh, *dbih, *dbhh;
  const float *pw, *pb, *gw, *gb;
  float *out, *ws;
};

// ws layout (float offsets)
constexpr long long XS_OFF    = 0;          // 400*32*256
constexpr long long PM_OFF    = 3276800;    // 32*128*384  pm[b][a][t]
constexpr long long PLOC_OFF  = 4849664;    // 32*128*384  plocpm[b][a][t]
constexpr long long AH0_OFF   = 6422528;    // 32*1024
constexpr long long AH1_OFF   = 6455296;
constexpr long long AC_OFF    = 6488064;
constexpr long long DH_OFF    = 6520832;
constexpr long long DC_OFF    = 6553600;
constexpr long long CTX0_OFF  = 6586368;    // 32*512
constexpr long long CTX1_OFF  = 6602752;
constexpr long long AW_OFF    = 6619136;    // 32*384
constexpr long long AWC_OFF   = 6631424;
constexpr long long DPART_OFF = 6643712;    // 32*4096
constexpr long long BAR_OFF   = 6774784;    // barrier counter (1 uint)
// total ~27.1 MB

// out layout
constexpr long long GATE0  = 1024000;   // after mel (32*80*400)
constexpr long long ALIGN0 = 1036800;   // after gate (32*400)

constexpr unsigned NBLK = 256;

union SMem {
  float pmstage[12][512];                                   // 24.6 KB
  struct { float x[5][80]; float l1[5][256]; } pre;
  struct { float x[32][68]; float g[64][32]; } gemm;        // pad 68
  struct { float awseg[2][224]; float cw[2][32][32]; float loc[32][196]; } ploc; // 35 KB max
  struct { float ah[1024]; float pq[128]; float pqp[2][128]; float vv[128];
           float e[384]; float w[384]; float red[16]; } row;
  struct { float hc[1536]; } mel;
};

__device__ __forceinline__ float sigf(float x){ return 1.0f/(1.0f+__expf(-x)); }
__device__ __forceinline__ float tanhfast(float x){ float e2 = __expf(2.0f*x); return 1.0f - 2.0f/(e2+1.0f); }

// software grid barrier: monotonic epoch counter, device-scope.
// Same mechanism the ROCm runtime uses for cooperative grid.sync().
__device__ __forceinline__ void gbar(unsigned* cnt, unsigned target){
  __syncthreads();
  if (threadIdx.x == 0){
    __threadfence();   // release: flush this CU's writes device-wide
    __hip_atomic_fetch_add(cnt, 1u, __ATOMIC_RELAXED, __HIP_MEMORY_SCOPE_AGENT);
    while (__hip_atomic_load(cnt, __ATOMIC_RELAXED, __HIP_MEMORY_SCOPE_AGENT) < target)
      __builtin_amdgcn_s_sleep(2);
    __threadfence();   // acquire: invalidate stale L1 before block proceeds
  }
  __syncthreads();
}

// cooperative load of a 32x64 fp32 tile (row stride 'stride' in src) into LDS
__device__ __forceinline__ void load_x32x64(float (*xs)[68], const float* src, int stride, int tid){
  #pragma unroll
  for (int j = 0; j < 2; ++j){
    int idx = tid*2 + j;                 // 0..511 float4s
    int row = idx >> 4, c4 = (idx & 15) << 2;
    float4 v = *reinterpret_cast<const float4*>(src + (long long)row*stride + c4);
    *reinterpret_cast<float4*>(&xs[row][c4]) = v;
  }
}

__global__ void init_kernel(float* ws){
  if (threadIdx.x == 0) *reinterpret_cast<unsigned*>(ws + BAR_OFF) = 0u;
}

__global__ __launch_bounds__(256, 2)
void decoder_kernel(Params P){
  __shared__ SMem sm;
  const int tid = threadIdx.x;
  const int bid = blockIdx.x;
  float* ws = P.ws;
  unsigned* bar = reinterpret_cast<unsigned*>(ws + BAR_OFF);
  unsigned epoch = 0;

  // ---------------- Prologue P0: zero states + processed_memory ----------------
  for (long long i = (long long)bid*256 + tid; i < 221184; i += 65536)
    ws[AH0_OFF + i] = 0.f;   // ah0,ah1,ac,dh,dc,ctx0,ctx1,aw,awc are contiguous

  {
    const int b = bid >> 3, tc3 = bid & 7;
    for (int sub = 0; sub < 4; ++sub){
      const int t0 = (tc3*4 + sub)*12;
      __syncthreads();
      for (int i = tid; i < 1536; i += 256){
        int row = i >> 7, c4 = (i & 127) << 2;
        *reinterpret_cast<float4*>(&sm.pmstage[row][c4]) =
          *reinterpret_cast<const float4*>(P.memory + ((long long)(b*384 + t0 + row))*512 + c4);
      }
      __syncthreads();
      const int a = tid & 127, th = tid >> 7;
      float acc[6] = {0,0,0,0,0,0};
      const float* mwr = P.mw + (long long)a*512;
      for (int e = 0; e < 512; ++e){
        float wv = mwr[e];
        #pragma unroll
        for (int jj = 0; jj < 6; ++jj) acc[jj] += wv*sm.pmstage[th*6+jj][e];
      }
      #pragma unroll
      for (int jj = 0; jj < 6; ++jj)
        ws[PM_OFF + ((long long)b*128 + a)*384 + t0 + th*6 + jj] = acc[jj];
    }
  }
  gbar(bar, (++epoch)*NBLK);

  // ---------------- Prologue P1: prenet (2 layers fused, 50 (t,b) pairs/block) --------
  {
    for (int batch = 0; batch < 10; ++batch){
      const int pbase = bid*50 + batch*5;
      __syncthreads();
      for (int i = tid; i < 400; i += 256){
        int j = i/80, m = i%80;
        int p = pbase + j; int tq = p >> 5, bb = p & 31;
        float v = 0.f;
        if (tq > 0) v = P.dec_in[((long long)bb*80 + m)*400 + (tq-1)];
        sm.pre.x[j][m] = v;
      }
      __syncthreads();
      {
        float acc[5] = {0,0,0,0,0};
        const float* w1r = P.w1 + (long long)tid*80;
        for (int m = 0; m < 80; ++m){
          float wv = w1r[m];
          #pragma unroll
          for (int j = 0; j < 5; ++j) acc[j] += wv*sm.pre.x[j][m];
        }
        __syncthreads();
        #pragma unroll
        for (int j = 0; j < 5; ++j) sm.pre.l1[j][tid] = fmaxf(acc[j], 0.f);
      }
      __syncthreads();
      {
        float acc[5] = {0,0,0,0,0};
        const float* w2r = P.w2 + (long long)tid*256;
        for (int pp = 0; pp < 256; ++pp){
          float wv = w2r[pp];
          #pragma unroll
          for (int j = 0; j < 5; ++j) acc[j] += wv*sm.pre.l1[j][pp];
        }
        #pragma unroll
        for (int j = 0; j < 5; ++j){
          int p = pbase + j; int tq = p >> 5, bb = p & 31;
          ws[XS_OFF + ((long long)tq*32 + bb)*256 + tid] = fmaxf(acc[j], 0.f);
        }
      }
    }
  }
  gbar(bar, (++epoch)*NBLK);

  // ---------------- Main loop: 2 grid barriers per step ----------------
  for (int t = 0; t <= 400; ++t){
    const int cur = t & 1, prv = (t+1) & 1;

    // ============ PHASE A ============
    if (bid < 128){
      // ---- attention-LSTM gates + cell (step t): 8 units/block ----
      if (t < 400){
        const int u0 = bid*8;
        const int r2 = tid >> 5;        // 0..7
        const int b  = tid & 31;
        float acc[4] = {0,0,0,0};
        const float* ah_old  = ws + (prv ? AH1_OFF : AH0_OFF);
        const float* ctx_old = ws + (prv ? CTX1_OFF : CTX0_OFF);
        for (int c = 0; c < 28; ++c){
          const int k0 = c*64;
          const float* src; int stride;
          if (k0 < 256){      src = ws + XS_OFF + (long long)t*8192 + k0; stride = 256; }
          else if (k0 < 768){ src = ctx_old + (k0-256); stride = 512; }
          else {              src = ah_old + (k0-768);  stride = 1024; }
          __syncthreads();
          load_x32x64(sm.gemm.x, src, stride, tid);
          __syncthreads();
          #pragma unroll
          for (int kk = 0; kk < 16; ++kk){
            float4 xv = *reinterpret_cast<const float4*>(&sm.gemm.x[b][kk*4]);
            #pragma unroll
            for (int j = 0; j < 4; ++j){
              const int rid = j*8 + r2;
              const int n = (rid>>3)*1024 + u0 + (rid&7);
              const float* wr = (k0 < 768) ? P.awih + (long long)n*768 + k0
                                           : P.awhh + (long long)n*1024 + (k0-768);
              float4 wv = *reinterpret_cast<const float4*>(wr + kk*4);
              acc[j] += wv.x*xv.x + wv.y*xv.y + wv.z*xv.z + wv.w*xv.w;
            }
          }
        }
        __syncthreads();
        #pragma unroll
        for (int j = 0; j < 4; ++j){
          const int rid = j*8 + r2;
          const int n = (rid>>3)*1024 + u0 + (rid&7);
          sm.gemm.g[rid][b] = acc[j] + P.abih[n] + P.abhh[n];
        }
        __syncthreads();
        {
          const int u = tid >> 5, bb = tid & 31;   // unit 0..7, batch
          float gi = sm.gemm.g[u][bb],     gf = sm.gemm.g[8+u][bb];
          float gg = sm.gemm.g[16+u][bb],  go = sm.gemm.g[24+u][bb];
          const long long idx = (long long)bb*1024 + u0 + u;
          float c2 = sigf(gf)*ws[AC_OFF+idx] + sigf(gi)*tanhfast(gg);
          ws[AC_OFF+idx] = c2;
          (ws + (cur ? AH1_OFF : AH0_OFF))[idx] = sigf(go)*tanhfast(c2);
        }
      }
    } else if (bid < 192){
      // ---- decoder-LSTM ctx-part + cell for step t-1: 16 units/block ----
      if (t >= 1){
        const int u0 = (bid-128)*16;
        const int r = tid >> 5;   // 0..7
        const int b = tid & 31;
        float acc[8] = {0,0,0,0,0,0,0,0};
        const float* ctx_old = ws + (prv ? CTX1_OFF : CTX0_OFF);  // ctx_{t-1}
        for (int c = 0; c < 8; ++c){
          const int k0 = c*64;
          __syncthreads();
          load_x32x64(sm.gemm.x, ctx_old + k0, 512, tid);
          __syncthreads();
          #pragma unroll
          for (int kk = 0; kk < 16; ++kk){
            float4 xv = *reinterpret_cast<const float4*>(&sm.gemm.x[b][kk*4]);
            #pragma unroll
            for (int j = 0; j < 8; ++j){
              const int rid = j*8 + r;
              const int n = (rid>>4)*1024 + u0 + (rid&15);
              float4 wv = *reinterpret_cast<const float4*>(P.dwih + (long long)n*1536 + 1024 + k0 + kk*4);
              acc[j] += wv.x*xv.x + wv.y*xv.y + wv.z*xv.z + wv.w*xv.w;
            }
          }
        }
        __syncthreads();
        #pragma unroll
        for (int j = 0; j < 8; ++j){
          const int rid = j*8 + r;
          const int n = (rid>>4)*1024 + u0 + (rid&15);
          sm.gemm.g[rid][b] = acc[j] + ws[DPART_OFF + (long long)b*4096 + n] + P.dbih[n] + P.dbhh[n];
        }
        __syncthreads();
        {
          const int bb = tid & 31;
          #pragma unroll
          for (int h = 0; h < 2; ++h){
            const int uu = (tid >> 5) + h*8;      // 0..15
            float gi = sm.gemm.g[uu][bb],       gf = sm.gemm.g[16+uu][bb];
            float gg = sm.gemm.g[32+uu][bb],    go = sm.gemm.g[48+uu][bb];
            const long long idx = (long long)bb*1024 + u0 + uu;
            float c2 = sigf(gf)*ws[DC_OFF+idx] + sigf(gi)*tanhfast(gg);
            ws[DC_OFF+idx] = c2;
            ws[DH_OFF+idx] = sigf(go)*tanhfast(c2);
          }
        }
      }
    } else {
      // ---- location conv + dense + pm -> plocpm (step t): one (b, 192-wide range)/block ----
      if (t < 400){
        const int j = bid - 192;
        const int b = j >> 1;
        const int tt0 = (j & 1)*192;
        if (tid < 222){
          int pos = tt0 - 15 + tid;
          bool ok = (pos >= 0 && pos < 384);
          sm.ploc.awseg[0][tid] = ok ? ws[AW_OFF  + b*384 + pos] : 0.f;
          sm.ploc.awseg[1][tid] = ok ? ws[AWC_OFF + b*384 + pos] : 0.f;
        }
        for (int i = tid; i < 1984; i += 256){
          int f = i/62, rem = i%62, cch = rem/31, k = rem%31;
          sm.ploc.cw[cch][f][k] = P.lcw[(long long)f*62 + cch*31 + k];
        }
        __syncthreads();
        {
          const int f = tid & 31, tb = tid >> 5;
          for (int it = 0; it < 24; ++it){
            const int tl = tb + it*8;
            float acc = 0.f;
            #pragma unroll
            for (int k = 0; k < 31; ++k)
              acc += sm.ploc.cw[0][f][k]*sm.ploc.awseg[0][tl+k]
                   + sm.ploc.cw[1][f][k]*sm.ploc.awseg[1][tl+k];
            sm.ploc.loc[f][tl] = acc;
          }
        }
        __syncthreads();
        {
          const int a = tid & 127, half = tid >> 7;
          float ldr[32];
          #pragma unroll
          for (int ff = 0; ff < 32; ++ff) ldr[ff] = P.ldw[(long long)a*32 + ff];
          const float* pmp = ws + PM_OFF   + ((long long)b*128 + a)*384 + tt0;
          float*      outp = ws + PLOC_OFF + ((long long)b*128 + a)*384 + tt0;
          for (int q = half*24; q < half*24 + 24; ++q){
            const int c0 = q*4;
            float4 acc4 = *reinterpret_cast<const float4*>(pmp + c0);
            #pragma unroll
            for (int ff = 0; ff < 32; ++ff){
              float4 l4 = *reinterpret_cast<const float4*>(&sm.ploc.loc[ff][c0]);
              acc4.x += ldr[ff]*l4.x; acc4.y += ldr[ff]*l4.y;
              acc4.z += ldr[ff]*l4.z; acc4.w += ldr[ff]*l4.w;
            }
            *reinterpret_cast<float4*>(outp + c0) = acc4;
          }
        }
      }
    }
    gbar(bar, (++epoch)*NBLK);

    // ============ PHASE B ============
    if (bid < 32){
      // ---- attention row block (step t): pq, e, softmax, ctx, awc, alignments ----
      if (t < 400){
        const int b = bid;
        const int len = P.memlen[b];
        const float* ahp = ws + (cur ? AH1_OFF : AH0_OFF) + (long long)b*1024;
        { float4 v = *reinterpret_cast<const float4*>(ahp + tid*4);
          *reinterpret_cast<float4*>(&sm.row.ah[tid*4]) = v; }
        if (tid < 128) sm.row.vv[tid] = P.vw[tid];
        __syncthreads();
        {
          const int a = tid & 127, kh = tid >> 7;
          const float* qr  = P.qw + (long long)a*1024 + kh*512;
          const float* ahs = &sm.row.ah[kh*512];
          float acc = 0.f;
          for (int k = 0; k < 512; k += 4){
            float4 wv = *reinterpret_cast<const float4*>(qr + k);
            acc += wv.x*ahs[k] + wv.y*ahs[k+1] + wv.z*ahs[k+2] + wv.w*ahs[k+3];
          }
          sm.row.pqp[kh][a] = acc;
        }
        __syncthreads();
        if (tid < 128) sm.row.pq[tid] = sm.row.pqp[0][tid] + sm.row.pqp[1][tid];
        __syncthreads();
        for (int tt = tid; tt < 384; tt += 256){
          float acc;
          if (tt < len){
            acc = 0.f;
            const float* pp = ws + PLOC_OFF + (long long)b*128*384 + tt;
            #pragma unroll 4
            for (int a = 0; a < 128; ++a)
              acc += sm.row.vv[a]*tanhfast(sm.row.pq[a] + pp[(long long)a*384]);
          } else acc = NEGV;
          sm.row.e[tt] = acc;
        }
        __syncthreads();
        float m = NEGV;
        for (int tt = tid; tt < 384; tt += 256) m = fmaxf(m, sm.row.e[tt]);
        for (int o = 32; o; o >>= 1) m = fmaxf(m, __shfl_xor(m, o, 64));
        if ((tid & 63) == 0) sm.row.red[tid >> 6] = m;
        __syncthreads();
        const float mx = fmaxf(fmaxf(sm.row.red[0], sm.row.red[1]),
                               fmaxf(sm.row.red[2], sm.row.red[3]));
        float s = 0.f;
        for (int tt = tid; tt < 384; tt += 256){
          float wv = (tt < len) ? __expf(sm.row.e[tt] - mx) : 0.f;
          sm.row.w[tt] = wv; s += wv;
        }
        for (int o = 32; o; o >>= 1) s += __shfl_xor(s, o, 64);
        if ((tid & 63) == 0) sm.row.red[8 + (tid >> 6)] = s;
        __syncthreads();
        const float inv = 1.f/(sm.row.red[8]+sm.row.red[9]+sm.row.red[10]+sm.row.red[11]);
        for (int tt = tid; tt < 384; tt += 256){
          float wv = sm.row.w[tt]*inv;
          sm.row.w[tt] = wv;
          ws[AW_OFF  + b*384 + tt] = wv;
          ws[AWC_OFF + b*384 + tt] += wv;
          P.out[ALIGN0 + ((long long)b*400 + t)*384 + tt] = wv;
        }
        __syncthreads();
        {
          float a0 = 0.f, a1 = 0.f;
          const float* mrow = P.memory + (long long)b*384*512;
          for (int tt = 0; tt < len; ++tt){
            float wv = sm.row.w[tt];
            a0 += wv*mrow[(long long)tt*512 + tid];
            a1 += wv*mrow[(long long)tt*512 + 256 + tid];
          }
          float* ctxp = ws + (cur ? CTX1_OFF : CTX0_OFF) + (long long)b*512;
          ctxp[tid] = a0; ctxp[tid+256] = a1;
        }
      }
    } else if (bid < 160){
      // ---- dec-LSTM ah/dh partial GEMM (step t): 32-row tile/block ----
      if (t < 400){
        const float* ahp = ws + (cur ? AH1_OFF : AH0_OFF);
        const int T8 = bid - 32;
        const int r = tid >> 5, b = tid & 31;
        float acc[4] = {0,0,0,0};
        for (int c = 0; c < 32; ++c){
          const int k0 = c*64;
          const float* src = (k0 < 1024) ? (ahp + k0) : (ws + DH_OFF + (k0-1024));
          __syncthreads();
          load_x32x64(sm.gemm.x, src, 1024, tid);
          __syncthreads();
          #pragma unroll
          for (int kk = 0; kk < 16; ++kk){
            float4 xv = *reinterpret_cast<const float4*>(&sm.gemm.x[b][kk*4]);
            #pragma unroll
            for (int j = 0; j < 4; ++j){
              const int n = T8*32 + j*8 + r;
              const float* wr = (k0 < 1024) ? (P.dwih + (long long)n*1536 + k0)
                                            : (P.dwhh + (long long)n*1024 + (k0-1024));
              float4 wv = *reinterpret_cast<const float4*>(wr + kk*4);
              acc[j] += wv.x*xv.x + wv.y*xv.y + wv.z*xv.z + wv.w*xv.w;
            }
          }
        }
        #pragma unroll
        for (int j = 0; j < 4; ++j){
          const int n = T8*32 + j*8 + r;
          ws[DPART_OFF + (long long)b*4096 + n] = acc[j];
        }
      }
    } else if (bid >= 224){
      // ---- mel + gate projections for step t-1 ----
      if (t >= 1){
        const int b = bid - 224;
        const float* dhp = ws + DH_OFF + (long long)b*1024;
        const float* cxp = ws + (prv ? CTX1_OFF : CTX0_OFF) + (long long)b*512;  // ctx_{t-1}
        for (int i = tid; i < 384; i += 256){
          float4 v;
          if (i < 256) v = *reinterpret_cast<const float4*>(dhp + i*4);
          else         v = *reinterpret_cast<const float4*>(cxp + (i-256)*4);
          *reinterpret_cast<float4*>(&sm.mel.hc[i*4]) = v;
        }
        __syncthreads();
        if (tid < 80){
          const float* pr = P.pw + (long long)tid*1536;
          float acc = P.pb[tid];
          for (int k = 0; k < 1536; k += 4){
            float4 wv = *reinterpret_cast<const float4*>(pr + k);
            acc += wv.x*sm.mel.hc[k] + wv.y*sm.mel.hc[k+1] + wv.z*sm.mel.hc[k+2] + wv.w*sm.mel.hc[k+3];
          }
          P.out[((long long)b*80 + tid)*400 + (t-1)] = acc;
        } else if (tid == 80){
          float acc = P.gb[0];
          for (int k = 0; k < 1536; ++k) acc += P.gw[k]*sm.mel.hc[k];
          P.out[GATE0 + (long long)b*400 + (t-1)] = acc;
        }
      }
    }
    gbar(bar, (++epoch)*NBLK);
  }
}

extern "C" void kernel_launch(void* const* d_in, const int* in_sizes, int n_in,
                              void* d_out, int out_size, void* d_ws, size_t ws_size,
                              hipStream_t stream) {
  (void)in_sizes; (void)n_in; (void)out_size; (void)ws_size;
  Params p;
  p.memory = (const float*)d_in[0];
  p.dec_in = (const float*)d_in[1];
  p.memlen = (const int*)d_in[2];
  p.w1   = (const float*)d_in[3];
  p.w2   = (const float*)d_in[4];
  p.awih = (const float*)d_in[5];
  p.awhh = (const float*)d_in[6];
  p.abih = (const float*)d_in[7];
  p.abhh = (const float*)d_in[8];
  p.qw   = (const float*)d_in[9];
  p.mw   = (const float*)d_in[10];
  p.vw   = (const float*)d_in[11];
  p.lcw  = (const float*)d_in[12];
  p.ldw  = (const float*)d_in[13];
  p.dwih = (const float*)d_in[14];
  p.dwhh = (const float*)d_in[15];
  p.dbih = (const float*)d_in[16];
  p.dbhh = (const float*)d_in[17];
  p.pw   = (const float*)d_in[18];
  p.pb   = (const float*)d_in[19];
  p.gw   = (const float*)d_in[20];
  p.gb   = (const float*)d_in[21];
  p.out  = (float*)d_out;
  p.ws   = (float*)d_ws;

  hipLaunchKernelGGL(init_kernel, dim3(1), dim3(64), 0, stream, p.ws);
  hipLaunchKernelGGL(decoder_kernel, dim3(256), dim3(256), 0, stream, p);
}

// Round 4
// 110289.685 us; speedup vs baseline: 1.3339x; 1.3339x over previous
//
#include <hip/hip_runtime.h>

#define NEGV -1000000000.0f

struct Params {
  const float *memory, *dec_in; const int *memlen;
  const float *w1, *w2;
  const float *awih, *awhh, *abih, *abhh;
  const float *qw, *mw, *vw, *lcw, *ldw;
  const float *dwih, *dwhh, *dbih, *dbhh;
  const float *pw, *pb, *gw, *gb;
  float *out, *ws;
};

// ws layout (float offsets)
constexpr long long XS_OFF   = 0;          // 400*32*256
constexpr long long PM_OFF   = 3276800;    // 32*128*384  pm[b][a][t] (fp32)
constexpr long long PLB_OFF  = 4849664;    // 32*128*384 bf16 (= 786432 floats) plocbf[b][a][t]
constexpr long long AH0_OFF  = 5636096;    // 32*1024
constexpr long long AH1_OFF  = 5668864;
constexpr long long AC_OFF   = 5701632;
constexpr long long DH_OFF   = 5734400;
constexpr long long DC_OFF   = 5767168;
constexpr long long CTX0_OFF = 5799936;    // 32*512
constexpr long long CTX1_OFF = 5816320;
constexpr long long AW_OFF   = 5832704;    // 32*384
constexpr long long AWC_OFF  = 5844992;
constexpr long long DPART_OFF= 5857280;    // 32*4096
constexpr long long BAR_OFF  = 5988352;    // 8 counters spaced 64 uints
// total ~24.0 MB

// out layout
constexpr long long GATE0  = 1024000;   // after mel (32*80*400)
constexpr long long ALIGN0 = 1036800;   // after gate (32*400)

constexpr unsigned NBLK = 512;

union SMem {
  float pmstage[12][512];                                   // 24.6 KB (max member)
  struct { float x[5][80]; float l1[5][256]; } pre;
  struct { float x[32][66]; float g[64][32]; } gemm;        // pitch 66: 2-way = free
  struct { float awseg[2][128]; float cw[2][32][32]; float loc[32][100]; } ploc;
  struct { float ah[1024]; float pq[128]; float pqp[2][128]; float vv[128];
           float e[384]; float w[384]; float red[16]; } row;
  struct { float hc[1536]; float mp[80][2]; float gacc; } mel;
};

__device__ __forceinline__ float sigf(float x){ return 1.0f/(1.0f+__expf(-x)); }
__device__ __forceinline__ float tanhfast(float x){ float e2 = __expf(2.0f*x); return 1.0f - 2.0f/(e2+1.0f); }

__device__ __forceinline__ unsigned short f2bf(float x){
  unsigned u = __float_as_uint(x);
  return (unsigned short)((u + 0x7FFFu + ((u>>16)&1u)) >> 16);
}
__device__ __forceinline__ float bf2f(unsigned short h){
  return __uint_as_float(((unsigned)h) << 16);
}

// software grid barrier, 8-way split counters to cut atomic serialization
__device__ __forceinline__ void gbar(unsigned* cnts, unsigned ep){
  __syncthreads();
  if (threadIdx.x == 0){
    __threadfence();   // release (L2 writeback, device scope)
    __hip_atomic_fetch_add(&cnts[(blockIdx.x & 7)*64], 1u, __ATOMIC_RELAXED, __HIP_MEMORY_SCOPE_AGENT);
    const unsigned tgt = ep * NBLK;
    for (;;){
      unsigned s = 0;
      #pragma unroll
      for (int i = 0; i < 8; ++i)
        s += __hip_atomic_load(&cnts[i*64], __ATOMIC_RELAXED, __HIP_MEMORY_SCOPE_AGENT);
      if (s >= tgt) break;
      __builtin_amdgcn_s_sleep(4);
    }
    __threadfence();   // acquire (L1/L2 invalidate)
  }
  __syncthreads();
}

// cooperative load of a 32x64 fp32 tile into LDS (pitch 66)
__device__ __forceinline__ void load_tile(float (*xs)[66], const float* src, int stride, int tid){
  #pragma unroll
  for (int j = 0; j < 2; ++j){
    int idx = tid*2 + j;                 // 0..511 float4s
    int row = idx >> 4, c4 = (idx & 15) << 2;
    float4 v = *reinterpret_cast<const float4*>(src + (long long)row*stride + c4);
    *reinterpret_cast<float2*>(&xs[row][c4])   = make_float2(v.x, v.y);
    *reinterpret_cast<float2*>(&xs[row][c4+2]) = make_float2(v.z, v.w);
  }
}

__global__ void init_kernel(float* ws){
  unsigned* c = reinterpret_cast<unsigned*>(ws + BAR_OFF);
  if (threadIdx.x < 512) c[threadIdx.x] = 0u;
}

__global__ __launch_bounds__(256, 2)
void decoder_kernel(Params P){
  __shared__ SMem sm;
  const int tid = threadIdx.x;
  const int bid = blockIdx.x;
  float* ws = P.ws;
  unsigned short* plb = reinterpret_cast<unsigned short*>(ws + PLB_OFF);
  unsigned* bar = reinterpret_cast<unsigned*>(ws + BAR_OFF);
  unsigned epoch = 0;

  // ---------------- Prologue P0: zero states + processed_memory ----------------
  for (long long i = (long long)bid*256 + tid; i < 221184; i += 131072)
    ws[AH0_OFF + i] = 0.f;   // ah0,ah1,ac,dh,dc,ctx0,ctx1,aw,awc contiguous

  {
    const int b = bid >> 4, part = bid & 15;
    for (int sub = 0; sub < 2; ++sub){
      const int t0 = part*24 + sub*12;
      __syncthreads();
      for (int i = tid; i < 1536; i += 256){
        int row = i >> 7, c4 = (i & 127) << 2;
        *reinterpret_cast<float4*>(&sm.pmstage[row][c4]) =
          *reinterpret_cast<const float4*>(P.memory + ((long long)(b*384 + t0 + row))*512 + c4);
      }
      __syncthreads();
      const int a = tid & 127, th = tid >> 7;
      float acc[6] = {0,0,0,0,0,0};
      const float* mwr = P.mw + (long long)a*512;
      for (int e = 0; e < 512; ++e){
        float wv = mwr[e];
        #pragma unroll
        for (int jj = 0; jj < 6; ++jj) acc[jj] += wv*sm.pmstage[th*6+jj][e];
      }
      #pragma unroll
      for (int jj = 0; jj < 6; ++jj)
        ws[PM_OFF + ((long long)b*128 + a)*384 + t0 + th*6 + jj] = acc[jj];
    }
  }
  gbar(bar, ++epoch);

  // ---------------- Prologue P1: prenet (25 (t,b) pairs/block) ----------------
  {
    for (int batch = 0; batch < 5; ++batch){
      const int pbase = bid*25 + batch*5;
      __syncthreads();
      for (int i = tid; i < 400; i += 256){
        int j = i/80, m = i%80;
        int p = pbase + j; int tq = p >> 5, bb = p & 31;
        float v = 0.f;
        if (tq > 0) v = P.dec_in[((long long)bb*80 + m)*400 + (tq-1)];
        sm.pre.x[j][m] = v;
      }
      __syncthreads();
      {
        float acc[5] = {0,0,0,0,0};
        const float* w1r = P.w1 + (long long)tid*80;
        for (int m = 0; m < 80; ++m){
          float wv = w1r[m];
          #pragma unroll
          for (int j = 0; j < 5; ++j) acc[j] += wv*sm.pre.x[j][m];
        }
        __syncthreads();
        #pragma unroll
        for (int j = 0; j < 5; ++j) sm.pre.l1[j][tid] = fmaxf(acc[j], 0.f);
      }
      __syncthreads();
      {
        float acc[5] = {0,0,0,0,0};
        const float* w2r = P.w2 + (long long)tid*256;
        for (int pp = 0; pp < 256; ++pp){
          float wv = w2r[pp];
          #pragma unroll
          for (int j = 0; j < 5; ++j) acc[j] += wv*sm.pre.l1[j][pp];
        }
        #pragma unroll
        for (int j = 0; j < 5; ++j){
          int p = pbase + j; int tq = p >> 5, bb = p & 31;
          ws[XS_OFF + ((long long)tq*32 + bb)*256 + tid] = fmaxf(acc[j], 0.f);
        }
      }
    }
  }
  gbar(bar, ++epoch);

  // ---------------- Main loop: 2 grid barriers per step ----------------
  for (int t = 0; t <= 400; ++t){
    const int cur = t & 1, prv = (t+1) & 1;

    // ============ PHASE A ============
    if (bid < 256){
      // ---- attention-LSTM gates + cell (step t): 4 units (16 rows)/block ----
      if (t < 400){
        const int u0 = bid*4;
        const int r2 = tid >> 5;        // 0..7; rows r2 and r2+8
        const int b  = tid & 31;
        const int g1 = r2 >> 2,     uu1 = r2 & 3;       const int n1 = g1*1024 + u0 + uu1;
        const int g2 = (r2+8) >> 2, uu2 = (r2+8) & 3;   const int n2 = g2*1024 + u0 + uu2;
        float acc0 = 0.f, acc1 = 0.f;
        const float* ah_old  = ws + (prv ? AH1_OFF : AH0_OFF);
        const float* ctx_old = ws + (prv ? CTX1_OFF : CTX0_OFF);
        for (int c = 0; c < 28; ++c){
          const int k0 = c*64;
          const float* src; int stride; const float *w0p, *w1p;
          if (k0 < 256){      src = ws + XS_OFF + (long long)t*8192 + k0; stride = 256; }
          else if (k0 < 768){ src = ctx_old + (k0-256); stride = 512; }
          else {              src = ah_old + (k0-768);  stride = 1024; }
          if (k0 < 768){ w0p = P.awih + (long long)n1*768 + k0;        w1p = P.awih + (long long)n2*768 + k0; }
          else         { w0p = P.awhh + (long long)n1*1024 + (k0-768); w1p = P.awhh + (long long)n2*1024 + (k0-768); }
          __syncthreads();
          load_tile(sm.gemm.x, src, stride, tid);
          __syncthreads();
          #pragma unroll
          for (int kk = 0; kk < 16; ++kk){
            float2 xa = *reinterpret_cast<const float2*>(&sm.gemm.x[b][kk*4]);
            float2 xb = *reinterpret_cast<const float2*>(&sm.gemm.x[b][kk*4+2]);
            float4 w0 = *reinterpret_cast<const float4*>(w0p + kk*4);
            float4 w1 = *reinterpret_cast<const float4*>(w1p + kk*4);
            acc0 += w0.x*xa.x + w0.y*xa.y + w0.z*xb.x + w0.w*xb.y;
            acc1 += w1.x*xa.x + w1.y*xa.y + w1.z*xb.x + w1.w*xb.y;
          }
        }
        __syncthreads();
        sm.gemm.g[r2][b]   = acc0 + P.abih[n1] + P.abhh[n1];
        sm.gemm.g[r2+8][b] = acc1 + P.abih[n2] + P.abhh[n2];
        __syncthreads();
        if (tid < 128){
          const int uu = tid >> 5, bb = tid & 31;     // unit 0..3
          float gi = sm.gemm.g[uu][bb],    gf = sm.gemm.g[4+uu][bb];
          float gg = sm.gemm.g[8+uu][bb],  go = sm.gemm.g[12+uu][bb];
          const long long idx = (long long)bb*1024 + u0 + uu;
          float c2 = sigf(gf)*ws[AC_OFF+idx] + sigf(gi)*tanhfast(gg);
          ws[AC_OFF+idx] = c2;
          (ws + (cur ? AH1_OFF : AH0_OFF))[idx] = sigf(go)*tanhfast(c2);
        }
      }
    } else if (bid < 384){
      // ---- decoder-LSTM ctx-part + cell for step t-1: 8 units (32 rows)/block ----
      if (t >= 1){
        const int u0 = (bid-256)*8;
        const int r = tid >> 5;   // 0..7; rows r, r+8, r+16, r+24
        const int b = tid & 31;
        float acc[4] = {0,0,0,0};
        const float* ctx_old = ws + (prv ? CTX1_OFF : CTX0_OFF);  // ctx_{t-1}
        for (int c = 0; c < 8; ++c){
          const int k0 = c*64;
          __syncthreads();
          load_tile(sm.gemm.x, ctx_old + k0, 512, tid);
          __syncthreads();
          #pragma unroll
          for (int kk = 0; kk < 16; ++kk){
            float2 xa = *reinterpret_cast<const float2*>(&sm.gemm.x[b][kk*4]);
            float2 xb = *reinterpret_cast<const float2*>(&sm.gemm.x[b][kk*4+2]);
            #pragma unroll
            for (int j = 0; j < 4; ++j){
              const int rid = j*8 + r;
              const int n = (rid>>3)*1024 + u0 + (rid&7);
              float4 wv = *reinterpret_cast<const float4*>(P.dwih + (long long)n*1536 + 1024 + k0 + kk*4);
              acc[j] += wv.x*xa.x + wv.y*xa.y + wv.z*xb.x + wv.w*xb.y;
            }
          }
        }
        __syncthreads();
        #pragma unroll
        for (int j = 0; j < 4; ++j){
          const int rid = j*8 + r;
          const int n = (rid>>3)*1024 + u0 + (rid&7);
          sm.gemm.g[rid][b] = acc[j] + ws[DPART_OFF + (long long)b*4096 + n] + P.dbih[n] + P.dbhh[n];
        }
        __syncthreads();
        {
          const int uu = tid >> 5, bb = tid & 31;     // unit 0..7
          float gi = sm.gemm.g[uu][bb],     gf = sm.gemm.g[8+uu][bb];
          float gg = sm.gemm.g[16+uu][bb],  go = sm.gemm.g[24+uu][bb];
          const long long idx = (long long)bb*1024 + u0 + uu;
          float c2 = sigf(gf)*ws[DC_OFF+idx] + sigf(gi)*tanhfast(gg);
          ws[DC_OFF+idx] = c2;
          ws[DH_OFF+idx] = sigf(go)*tanhfast(c2);
        }
      }
    } else {
      // ---- loc conv + dense + pm -> plocbf (step t): (b, 96-wide t'-range)/block ----
      if (t < 400){
        const int j = bid - 384;
        const int b = j >> 2;
        const int tbase = (j & 3)*96;
        if (tid < 126){
          int pos = tbase - 15 + tid;
          bool ok = (pos >= 0 && pos < 384);
          sm.ploc.awseg[0][tid] = ok ? ws[AW_OFF  + b*384 + pos] : 0.f;
          sm.ploc.awseg[1][tid] = ok ? ws[AWC_OFF + b*384 + pos] : 0.f;
        }
        for (int i = tid; i < 1984; i += 256){
          int f = i/62, rem = i%62, cch = rem/31, k = rem%31;
          sm.ploc.cw[cch][f][k] = P.lcw[(long long)f*62 + cch*31 + k];
        }
        __syncthreads();
        {
          const int f = tid & 31, tb = tid >> 5;
          for (int it = 0; it < 12; ++it){
            const int tl = tb + it*8;       // 0..95
            float acc = 0.f;
            #pragma unroll
            for (int k = 0; k < 31; ++k)
              acc += sm.ploc.cw[0][f][k]*sm.ploc.awseg[0][tl+k]
                   + sm.ploc.cw[1][f][k]*sm.ploc.awseg[1][tl+k];
            sm.ploc.loc[f][tl] = acc;
          }
        }
        __syncthreads();
        {
          const int a = tid & 127, h = tid >> 7;   // h: t'-half (48 each)
          float lw[32];
          #pragma unroll
          for (int ff = 0; ff < 32; ++ff) lw[ff] = P.ldw[(long long)a*32 + ff];
          const float* pmp = ws + PM_OFF + ((long long)b*128 + a)*384 + tbase;
          for (int pass = 0; pass < 3; ++pass){
            const int t0 = h*48 + pass*16;
            float4 acc4[4];
            #pragma unroll
            for (int u = 0; u < 4; ++u)
              acc4[u] = *reinterpret_cast<const float4*>(pmp + t0 + u*4);
            #pragma unroll
            for (int ff = 0; ff < 32; ++ff){
              float lv = lw[ff];
              #pragma unroll
              for (int u = 0; u < 4; ++u){
                float4 l4 = *reinterpret_cast<const float4*>(&sm.ploc.loc[ff][t0 + u*4]);
                acc4[u].x += lv*l4.x; acc4[u].y += lv*l4.y;
                acc4[u].z += lv*l4.z; acc4[u].w += lv*l4.w;
              }
            }
            #pragma unroll
            for (int u = 0; u < 4; ++u){
              uint2 pk;
              pk.x = (unsigned)f2bf(acc4[u].x) | ((unsigned)f2bf(acc4[u].y) << 16);
              pk.y = (unsigned)f2bf(acc4[u].z) | ((unsigned)f2bf(acc4[u].w) << 16);
              *reinterpret_cast<uint2*>(&plb[((long long)b*128 + a)*384 + tbase + t0 + u*4]) = pk;
            }
          }
        }
      }
    }
    gbar(bar, ++epoch);

    // ============ PHASE B ============
    if (bid < 32){
      // ---- attention (step t): pq, e, softmax, ctx, awc, alignments ----
      if (t < 400){
        const int b = bid;
        const int len = P.memlen[b];
        const float* ahp = ws + (cur ? AH1_OFF : AH0_OFF) + (long long)b*1024;
        { float4 v = *reinterpret_cast<const float4*>(ahp + tid*4);
          *reinterpret_cast<float4*>(&sm.row.ah[tid*4]) = v; }
        if (tid < 128) sm.row.vv[tid] = P.vw[tid];
        __syncthreads();
        {
          const int a = tid & 127, kh = tid >> 7;
          const float* qr  = P.qw + (long long)a*1024 + kh*512;
          const float* ahs = &sm.row.ah[kh*512];
          float acc = 0.f;
          for (int k = 0; k < 512; k += 4){
            float4 wv = *reinterpret_cast<const float4*>(qr + k);
            acc += wv.x*ahs[k] + wv.y*ahs[k+1] + wv.z*ahs[k+2] + wv.w*ahs[k+3];
          }
          sm.row.pqp[kh][a] = acc;
        }
        __syncthreads();
        if (tid < 128) sm.row.pq[tid] = sm.row.pqp[0][tid] + sm.row.pqp[1][tid];
        __syncthreads();
        for (int pass = 0; pass < 2; ++pass){
          const int tt = tid + pass*256;
          if (tt < 384){
            float acc;
            if (tt < len){
              acc = 0.f;
              const unsigned short* plp = plb + (long long)b*128*384 + tt;
              #pragma unroll 4
              for (int a = 0; a < 128; ++a)
                acc += sm.row.vv[a]*tanhfast(sm.row.pq[a] + bf2f(plp[(long long)a*384]));
            } else acc = NEGV;
            sm.row.e[tt] = acc;
          }
        }
        __syncthreads();
        float m = NEGV;
        for (int tt = tid; tt < 384; tt += 256) m = fmaxf(m, sm.row.e[tt]);
        for (int o = 32; o; o >>= 1) m = fmaxf(m, __shfl_xor(m, o, 64));
        if ((tid & 63) == 0) sm.row.red[tid >> 6] = m;
        __syncthreads();
        const float mx = fmaxf(fmaxf(sm.row.red[0], sm.row.red[1]),
                               fmaxf(sm.row.red[2], sm.row.red[3]));
        float s = 0.f;
        for (int tt = tid; tt < 384; tt += 256){
          float wv = (tt < len) ? __expf(sm.row.e[tt] - mx) : 0.f;
          sm.row.w[tt] = wv; s += wv;
        }
        for (int o = 32; o; o >>= 1) s += __shfl_xor(s, o, 64);
        if ((tid & 63) == 0) sm.row.red[8 + (tid >> 6)] = s;
        __syncthreads();
        const float inv = 1.f/(sm.row.red[8]+sm.row.red[9]+sm.row.red[10]+sm.row.red[11]);
        for (int tt = tid; tt < 384; tt += 256){
          float wv = sm.row.w[tt]*inv;
          sm.row.w[tt] = wv;
          ws[AW_OFF  + b*384 + tt] = wv;
          ws[AWC_OFF + b*384 + tt] += wv;
          P.out[ALIGN0 + ((long long)b*400 + t)*384 + tt] = wv;
        }
        __syncthreads();
        {
          float a0 = 0.f, a1 = 0.f;
          const float* mrow = P.memory + (long long)b*384*512;
          for (int tt = 0; tt < len; ++tt){
            float wv = sm.row.w[tt];
            a0 += wv*mrow[(long long)tt*512 + tid];
            a1 += wv*mrow[(long long)tt*512 + 256 + tid];
          }
          float* ctxp = ws + (cur ? CTX1_OFF : CTX0_OFF) + (long long)b*512;
          ctxp[tid] = a0; ctxp[tid+256] = a1;
        }
      }
    } else if (bid < 288){
      // ---- dec-LSTM ah/dh partial GEMM (step t): 16 rows/block ----
      if (t < 400){
        const float* ahp = ws + (cur ? AH1_OFF : AH0_OFF);
        const int T = bid - 32;
        const int r2 = tid >> 5, b = tid & 31;
        const int n0 = T*16 + r2, n1 = T*16 + r2 + 8;
        float acc0 = 0.f, acc1 = 0.f;
        for (int c = 0; c < 32; ++c){
          const int k0 = c*64;
          const float* src; const float *w0p, *w1p;
          if (k0 < 1024){ src = ahp + k0;
                          w0p = P.dwih + (long long)n0*1536 + k0;
                          w1p = P.dwih + (long long)n1*1536 + k0; }
          else          { src = ws + DH_OFF + (k0-1024);
                          w0p = P.dwhh + (long long)n0*1024 + (k0-1024);
                          w1p = P.dwhh + (long long)n1*1024 + (k0-1024); }
          __syncthreads();
          load_tile(sm.gemm.x, src, 1024, tid);
          __syncthreads();
          #pragma unroll
          for (int kk = 0; kk < 16; ++kk){
            float2 xa = *reinterpret_cast<const float2*>(&sm.gemm.x[b][kk*4]);
            float2 xb = *reinterpret_cast<const float2*>(&sm.gemm.x[b][kk*4+2]);
            float4 w0 = *reinterpret_cast<const float4*>(w0p + kk*4);
            float4 w1 = *reinterpret_cast<const float4*>(w1p + kk*4);
            acc0 += w0.x*xa.x + w0.y*xa.y + w0.z*xb.x + w0.w*xb.y;
            acc1 += w1.x*xa.x + w1.y*xa.y + w1.z*xb.x + w1.w*xb.y;
          }
        }
        ws[DPART_OFF + (long long)b*4096 + n0] = acc0;
        ws[DPART_OFF + (long long)b*4096 + n1] = acc1;
      }
    } else if (bid < 320){
      // ---- mel + gate projections for step t-1 ----
      if (t >= 1){
        const int b = bid - 288;
        const float* dhp = ws + DH_OFF + (long long)b*1024;
        const float* cxp = ws + (prv ? CTX1_OFF : CTX0_OFF) + (long long)b*512;  // ctx_{t-1}
        for (int i = tid; i < 384; i += 256){
          float4 v;
          if (i < 256) v = *reinterpret_cast<const float4*>(dhp + i*4);
          else         v = *reinterpret_cast<const float4*>(cxp + (i-256)*4);
          *reinterpret_cast<float4*>(&sm.mel.hc[i*4]) = v;
        }
        __syncthreads();
        if (tid < 160){
          const int r = tid >> 1, h = tid & 1;
          const float* pr  = P.pw + (long long)r*1536 + h*768;
          const float* hcp = &sm.mel.hc[h*768];
          float acc = 0.f;
          for (int k = 0; k < 768; k += 4){
            float4 wv = *reinterpret_cast<const float4*>(pr + k);
            acc += wv.x*hcp[k] + wv.y*hcp[k+1] + wv.z*hcp[k+2] + wv.w*hcp[k+3];
          }
          sm.mel.mp[r][h] = acc;
        } else if (tid >= 192){
          const int l = tid - 192;
          const float* gp  = P.gw + l*24;
          const float* hcp = &sm.mel.hc[l*24];
          float acc = 0.f;
          #pragma unroll
          for (int k = 0; k < 24; ++k) acc += gp[k]*hcp[k];
          for (int o = 32; o; o >>= 1) acc += __shfl_xor(acc, o, 64);
          if (l == 0) sm.mel.gacc = acc;
        }
        __syncthreads();
        if (tid < 80)
          P.out[((long long)b*80 + tid)*400 + (t-1)] = sm.mel.mp[tid][0] + sm.mel.mp[tid][1] + P.pb[tid];
        if (tid == 80)
          P.out[GATE0 + (long long)b*400 + (t-1)] = sm.mel.gacc + P.gb[0];
      }
    }
    gbar(bar, ++epoch);
  }
}

extern "C" void kernel_launch(void* const* d_in, const int* in_sizes, int n_in,
                              void* d_out, int out_size, void* d_ws, size_t ws_size,
                              hipStream_t stream) {
  (void)in_sizes; (void)n_in; (void)out_size; (void)ws_size;
  Params p;
  p.memory = (const float*)d_in[0];
  p.dec_in = (const float*)d_in[1];
  p.memlen = (const int*)d_in[2];
  p.w1   = (const float*)d_in[3];
  p.w2   = (const float*)d_in[4];
  p.awih = (const float*)d_in[5];
  p.awhh = (const float*)d_in[6];
  p.abih = (const float*)d_in[7];
  p.abhh = (const float*)d_in[8];
  p.qw   = (const float*)d_in[9];
  p.mw   = (const float*)d_in[10];
  p.vw   = (const float*)d_in[11];
  p.lcw  = (const float*)d_in[12];
  p.ldw  = (const float*)d_in[13];
  p.dwih = (const float*)d_in[14];
  p.dwhh = (const float*)d_in[15];
  p.dbih = (const float*)d_in[16];
  p.dbhh = (const float*)d_in[17];
  p.pw   = (const float*)d_in[18];
  p.pb   = (const float*)d_in[19];
  p.gw   = (const float*)d_in[20];
  p.gb   = (const float*)d_in[21];
  p.out  = (float*)d_out;
  p.ws   = (float*)d_ws;

  hipLaunchKernelGGL(init_kernel, dim3(1), dim3(512), 0, stream, p.ws);
  hipLaunchKernelGGL(decoder_kernel, dim3(512), dim3(256), 0, stream, p);
}

// Round 5
// 54211.841 us; speedup vs baseline: 2.7138x; 2.0344x over previous
//
#include <hip/hip_runtime.h>

typedef _Float16 h16;
typedef _Float16 half8 __attribute__((ext_vector_type(8)));
typedef float f32x4 __attribute__((ext_vector_type(4)));

#define NEGV -1000000000.0f
#define MFMA16(a,b,c) __builtin_amdgcn_mfma_f32_16x16x32_f16(a,b,c,0,0,0)

struct Params {
  const float *memory, *dec_in; const int *memlen;
  const float *w1, *w2;
  const float *awih, *awhh, *abih, *abhh;
  const float *qw, *mw, *vw, *lcw, *ldw;
  const float *dwih, *dwhh, *dbih, *dbhh;
  const float *pw, *pb, *gw, *gb;
  float *out, *ws;
};

// ---- ws layout ----
// f16 arrays: offsets in HALFS
constexpr long long XALLF_H = 0;          // 400*32*256  xallf[t][b][256]
constexpr long long PMH_H   = 3276800;    // 32*128*384  pm[b][a][t]
constexpr long long PLB_H   = 4849664;    // 32*384*128  plb[b][t][a]
constexpr long long AWIHF_H = 6422528;    // 4096*768
constexpr long long AWHHF_H = 9568256;    // 4096*1024
constexpr long long DWIHF_H = 13762560;   // 4096*1536
constexpr long long DWHHF_H = 20054016;   // 4096*1024
constexpr long long LCWF_H  = 24248320;   // 32*64 (padded conv wts, f-major)
constexpr long long LDWF_H  = 24250368;   // 128*32 (a-major)
constexpr long long AHF_H   = 24254464;   // 2 * 32*1024 (double buffered)
constexpr long long DHF_H   = 24320000;   // 32*1024
constexpr long long CTXF_H  = 24352768;   // 32*512
// fp32 arrays: offsets in FLOATS
constexpr long long ZERO_F0 = 12127232;   // zero region start (covers AHF..DPART)
constexpr long long AC_F    = 12184576;   // 32*1024
constexpr long long DC_F    = 12217344;   // 32*1024
constexpr long long AW_F    = 12250112;   // 32*384
constexpr long long AWC_F   = 12262400;   // 32*384
constexpr long long DPART_F = 12274688;   // 32*4096
constexpr long long BAR_F   = 12405760;   // 512 uints
constexpr int  ZERO_LEN = 278528;
constexpr unsigned NBLK = 512;
// out layout
constexpr long long GATE0  = 1024000;
constexpr long long ALIGN0 = 1036800;

union SMem {
  float pmstage[12][512];                                     // 24.6 KB
  struct { float x[5][80]; float l1[5][256]; } pre;
  struct { float red[4][2][16][17]; } g;                      // 8.7 KB
  struct { float awseg[2][128]; h16 im2[96][72]; h16 locT[96][32];
           unsigned p16[96][64]; } ploc;                      // 45.6 KB (max)
  struct { float ah[1024]; float pq[128]; float pqp[2][128]; float vv[128];
           float e[384]; float w[384]; float red[16]; } row;
  struct { float hc[1536]; float mp[80][2]; float gacc; } mel;
};

__device__ __forceinline__ float sigf(float x){ return 1.0f/(1.0f+__expf(-x)); }
__device__ __forceinline__ float tanhfast(float x){ float e2 = __expf(2.0f*x); return 1.0f - 2.0f/(e2+1.0f); }

// ---- agent-scope (cross-XCD coherent, cache-bypassing) accessors ----
__device__ __forceinline__ float aldf(const float* p){
  return __hip_atomic_load(p, __ATOMIC_RELAXED, __HIP_MEMORY_SCOPE_AGENT);
}
__device__ __forceinline__ void astf(float* p, float v){
  __hip_atomic_store(p, v, __ATOMIC_RELAXED, __HIP_MEMORY_SCOPE_AGENT);
}
__device__ __forceinline__ unsigned long long aldu64(const h16* p){
  return __hip_atomic_load((const unsigned long long*)p, __ATOMIC_RELAXED, __HIP_MEMORY_SCOPE_AGENT);
}
__device__ __forceinline__ half8 ald16(const h16* p){
  union { unsigned long long q[2]; half8 v; } u;
  u.q[0] = __hip_atomic_load((const unsigned long long*)p,     __ATOMIC_RELAXED, __HIP_MEMORY_SCOPE_AGENT);
  u.q[1] = __hip_atomic_load(((const unsigned long long*)p)+1, __ATOMIC_RELAXED, __HIP_MEMORY_SCOPE_AGENT);
  return u.v;
}
__device__ __forceinline__ void asth(h16* p, float v){
  union { h16 h; unsigned short s; } u; u.h = (h16)v;
  __hip_atomic_store((unsigned short*)p, u.s, __ATOMIC_RELAXED, __HIP_MEMORY_SCOPE_AGENT);
}
__device__ __forceinline__ void astu32(unsigned* p, unsigned v){
  __hip_atomic_store(p, v, __ATOMIC_RELAXED, __HIP_MEMORY_SCOPE_AGENT);
}

// software grid barrier; full=true adds release/acquire cache maintenance
__device__ __forceinline__ void gbar(unsigned* cnts, unsigned ep, bool full){
  __syncthreads();
  if (threadIdx.x == 0){
    if (full) __threadfence();
    __hip_atomic_fetch_add(&cnts[(blockIdx.x & 7)*64], 1u, __ATOMIC_RELEASE, __HIP_MEMORY_SCOPE_AGENT);
    const unsigned tgt = ep*NBLK;
    for (;;){
      unsigned s = 0;
      #pragma unroll
      for (int i = 0; i < 8; ++i)
        s += __hip_atomic_load(&cnts[i*64], __ATOMIC_RELAXED, __HIP_MEMORY_SCOPE_AGENT);
      if (s >= tgt) break;
      __builtin_amdgcn_s_sleep(4);
    }
    if (full) __threadfence();
  }
  __syncthreads();
}

__global__ void init_kernel(float* ws){
  unsigned* c = (unsigned*)(ws + BAR_F);
  if (threadIdx.x < 512) c[threadIdx.x] = 0u;
}

__global__ __launch_bounds__(256, 2)
void decoder_kernel(Params P){
  __shared__ SMem sm;
  const int tid = threadIdx.x;
  const int bid = blockIdx.x;
  float* ws = P.ws;
  h16*   wsh = (h16*)ws;
  unsigned* bar = (unsigned*)(ws + BAR_F);
  unsigned ep = 0;

  const int lane = tid & 63, wv = tid >> 6;
  const int i16 = lane & 15, q = lane >> 4;

  // ============== PROLOGUE ==============
  {
    const long long gtid = (long long)bid*256 + tid;
    // zero state region
    for (long long i = gtid; i < ZERO_LEN; i += 131072) ws[ZERO_F0 + i] = 0.f;
    // weight f16 conversion
    for (long long i = gtid; i < 3145728; i += 131072) wsh[AWIHF_H+i] = (h16)P.awih[i];
    for (long long i = gtid; i < 4194304; i += 131072) wsh[AWHHF_H+i] = (h16)P.awhh[i];
    for (long long i = gtid; i < 6291456; i += 131072) wsh[DWIHF_H+i] = (h16)P.dwih[i];
    for (long long i = gtid; i < 4194304; i += 131072) wsh[DWHHF_H+i] = (h16)P.dwhh[i];
    for (long long i = gtid; i < 2048; i += 131072){
      int f = (int)(i >> 6), kk = (int)(i & 63), ch = kk >> 5, k = kk & 31;
      wsh[LCWF_H+i] = (k < 31) ? (h16)P.lcw[f*62 + ch*31 + k] : (h16)0.f;
    }
    for (long long i = gtid; i < 4096; i += 131072) wsh[LDWF_H+i] = (h16)P.ldw[i];
  }
  // processed_memory -> PMH (f16)
  {
    const int b = bid >> 4, part = bid & 15;
    for (int sub = 0; sub < 2; ++sub){
      const int t0 = part*24 + sub*12;
      __syncthreads();
      for (int i = tid; i < 1536; i += 256){
        int row = i >> 7, c4 = (i & 127) << 2;
        *reinterpret_cast<float4*>(&sm.pmstage[row][c4]) =
          *reinterpret_cast<const float4*>(P.memory + ((long long)(b*384 + t0 + row))*512 + c4);
      }
      __syncthreads();
      const int a = tid & 127, th = tid >> 7;
      float acc[6] = {0,0,0,0,0,0};
      const float* mwr = P.mw + (long long)a*512;
      for (int e = 0; e < 512; ++e){
        float wvv = mwr[e];
        #pragma unroll
        for (int jj = 0; jj < 6; ++jj) acc[jj] += wvv*sm.pmstage[th*6+jj][e];
      }
      #pragma unroll
      for (int jj = 0; jj < 6; ++jj)
        wsh[PMH_H + ((long long)b*128 + a)*384 + t0 + th*6 + jj] = (h16)acc[jj];
    }
  }
  // prenet -> XALLF (f16)
  {
    for (int batch = 0; batch < 5; ++batch){
      const int pbase = bid*25 + batch*5;
      __syncthreads();
      for (int i = tid; i < 400; i += 256){
        int j = i/80, m = i%80;
        int p = pbase + j; int tq = p >> 5, bb = p & 31;
        float v = 0.f;
        if (tq > 0) v = P.dec_in[((long long)bb*80 + m)*400 + (tq-1)];
        sm.pre.x[j][m] = v;
      }
      __syncthreads();
      {
        float acc[5] = {0,0,0,0,0};
        const float* w1r = P.w1 + (long long)tid*80;
        for (int m = 0; m < 80; ++m){
          float wvv = w1r[m];
          #pragma unroll
          for (int j = 0; j < 5; ++j) acc[j] += wvv*sm.pre.x[j][m];
        }
        __syncthreads();
        #pragma unroll
        for (int j = 0; j < 5; ++j) sm.pre.l1[j][tid] = fmaxf(acc[j], 0.f);
      }
      __syncthreads();
      {
        float acc[5] = {0,0,0,0,0};
        const float* w2r = P.w2 + (long long)tid*256;
        for (int pp = 0; pp < 256; ++pp){
          float wvv = w2r[pp];
          #pragma unroll
          for (int j = 0; j < 5; ++j) acc[j] += wvv*sm.pre.l1[j][pp];
        }
        #pragma unroll
        for (int j = 0; j < 5; ++j){
          int p = pbase + j; int tq = p >> 5, bb = p & 31;
          wsh[XALLF_H + ((long long)tq*32 + bb)*256 + tid] = (h16)fmaxf(acc[j], 0.f);
        }
      }
    }
  }
  gbar(bar, ++ep, true);   // full fence once: weights/PMH/XALLF now visible + cached

  // ============== MAIN LOOP ==============
  for (int t = 0; t <= 400; ++t){
    const int cur = t & 1, prv = (t+1) & 1;

    // ---------- PHASE A ----------
    if (bid < 256){
      // att-LSTM: 4 units/block via MFMA, waves split K (56 steps = 4x14)
      if (t < 400){
        const int u0 = bid*4;
        const int n = ((i16 >> 2)*1024) + u0 + (i16 & 3);   // gate-gathered row
        f32x4 acc0 = {0,0,0,0}, acc1 = {0,0,0,0};
        const long long prvO = (long long)prv*32768;
        for (int s = wv*14; s < wv*14 + 14; ++s){
          const int k0 = s*32;
          const h16* pA = (k0 < 768) ? wsh + AWIHF_H + (long long)n*768 + k0 + q*8
                                     : wsh + AWHHF_H + (long long)n*1024 + (k0-768) + q*8;
          half8 A = *(const half8*)pA;
          half8 B0, B1;
          if (k0 < 256){
            B0 = *(const half8*)(wsh + XALLF_H + ((long long)t*32 + i16)*256 + k0 + q*8);
            B1 = *(const half8*)(wsh + XALLF_H + ((long long)t*32 + 16 + i16)*256 + k0 + q*8);
          } else if (k0 < 768){
            B0 = ald16(wsh + CTXF_H + i16*512 + (k0-256) + q*8);
            B1 = ald16(wsh + CTXF_H + (16+i16)*512 + (k0-256) + q*8);
          } else {
            B0 = ald16(wsh + AHF_H + prvO + i16*1024 + (k0-768) + q*8);
            B1 = ald16(wsh + AHF_H + prvO + (16+i16)*1024 + (k0-768) + q*8);
          }
          acc0 = MFMA16(A, B0, acc0);
          acc1 = MFMA16(A, B1, acc1);
        }
        #pragma unroll
        for (int r = 0; r < 4; ++r){
          sm.g.red[wv][0][q*4+r][i16] = acc0[r];
          sm.g.red[wv][1][q*4+r][i16] = acc1[r];
        }
        __syncthreads();
        if (tid < 128){
          const int uu = tid >> 5, b = tid & 31;
          const int bt = b >> 4, c = b & 15;
          float g4[4];
          #pragma unroll
          for (int g = 0; g < 4; ++g){
            const int tr = g*4 + uu;
            float v = sm.g.red[0][bt][tr][c] + sm.g.red[1][bt][tr][c]
                    + sm.g.red[2][bt][tr][c] + sm.g.red[3][bt][tr][c];
            const int ng = g*1024 + u0 + uu;
            g4[g] = v + P.abih[ng] + P.abhh[ng];
          }
          const long long idx = (long long)b*1024 + u0 + uu;
          float c2 = sigf(g4[1])*ws[AC_F + idx] + sigf(g4[0])*tanhfast(g4[2]);
          ws[AC_F + idx] = c2;
          asth(wsh + AHF_H + (long long)cur*32768 + idx, sigf(g4[3])*tanhfast(c2));
        }
      }
    } else if (bid < 384){
      // loc conv + dense via MFMA -> plb f16 [b][t'][a]
      if (t < 400){
        const int pb = bid - 256, b = pb >> 2, tbase = (pb & 3)*96;
        for (int i = tid; i < 252; i += 256){
          int ch = i / 126, ix = i % 126;
          int pos = tbase - 15 + ix;
          float v = 0.f;
          if (pos >= 0 && pos < 384)
            v = aldf(ws + (ch ? AWC_F : AW_F) + b*384 + pos);
          sm.ploc.awseg[ch][ix] = v;
        }
        __syncthreads();
        for (int i = tid; i < 96*64; i += 256){
          int tt = i >> 6, kk = i & 63, ch = kk >> 5, k = kk & 31;
          sm.ploc.im2[tt][kk] = (k < 31) ? (h16)sm.ploc.awseg[ch][tt + k] : (h16)0.f;
        }
        __syncthreads();
        // conv: out[t'][f] = sum_k im2[t'][k] * lcwf[f][k]; 12 tiles, 3/wave
        #pragma unroll
        for (int p = 0; p < 3; ++p){
          int tile = wv + p*4;
          int tT = tile % 6, tF = tile / 6;
          f32x4 a = {0,0,0,0};
          #pragma unroll
          for (int ks = 0; ks < 2; ++ks){
            half8 A = *(const half8*)&sm.ploc.im2[tT*16 + i16][ks*32 + q*8];
            half8 B = *(const half8*)(wsh + LCWF_H + (tF*16 + i16)*64 + ks*32 + q*8);
            a = MFMA16(A, B, a);
          }
          #pragma unroll
          for (int r = 0; r < 4; ++r)
            sm.ploc.locT[tT*16 + q*4 + r][tF*16 + i16] = (h16)a[r];
        }
        __syncthreads();
        // dense: plb[t'][a] = pm + sum_f locT[t'][f]*ldw[a][f]; 48 tiles, 12/wave
        unsigned short* s16 = (unsigned short*)&sm.ploc.p16[0][0];
        #pragma unroll
        for (int p = 0; p < 12; ++p){
          int tile = wv + p*4;
          int tT = tile % 6, tA = tile / 6;
          half8 A = *(const half8*)&sm.ploc.locT[tT*16 + i16][q*8];
          half8 B = *(const half8*)(wsh + LDWF_H + (tA*16 + i16)*32 + q*8);
          f32x4 a = {0,0,0,0};
          a = MFMA16(A, B, a);
          int aa = tA*16 + i16;
          union { unsigned long long u; h16 h[4]; } pmu;
          pmu.u = *(const unsigned long long*)
              (wsh + PMH_H + ((long long)b*128 + aa)*384 + tbase + tT*16 + q*4);
          #pragma unroll
          for (int r = 0; r < 4; ++r){
            union { h16 h; unsigned short s; } cv;
            cv.h = (h16)(a[r] + (float)pmu.h[r]);
            s16[(tT*16 + q*4 + r)*128 + aa] = cv.s;
          }
        }
        __syncthreads();
        unsigned* plbu = (unsigned*)(wsh + PLB_H);
        for (int i = tid; i < 96*64; i += 256){
          int tt = i >> 6, a2 = i & 63;
          astu32(plbu + ((long long)b*384 + tbase + tt)*64 + a2, sm.ploc.p16[tt][a2]);
        }
      }
    } else {
      // dec-LSTM ctx-part (K=512) + cell for step t-1: 8 units/block
      if (t >= 1){
        const int u0 = (bid-384)*8;
        const int jt = wv & 1, kh = wv >> 1;
        const int n = ((i16 >> 2)*1024) + u0 + jt*4 + (i16 & 3);
        f32x4 acc0 = {0,0,0,0}, acc1 = {0,0,0,0};
        for (int s = kh*8; s < kh*8 + 8; ++s){
          const int k0 = s*32;
          half8 A = *(const half8*)(wsh + DWIHF_H + (long long)n*1536 + 1024 + k0 + q*8);
          half8 B0 = ald16(wsh + CTXF_H + i16*512 + k0 + q*8);
          half8 B1 = ald16(wsh + CTXF_H + (16+i16)*512 + k0 + q*8);
          acc0 = MFMA16(A, B0, acc0);
          acc1 = MFMA16(A, B1, acc1);
        }
        #pragma unroll
        for (int r = 0; r < 4; ++r){
          sm.g.red[wv][0][q*4+r][i16] = acc0[r];
          sm.g.red[wv][1][q*4+r][i16] = acc1[r];
        }
        __syncthreads();
        {
          const int uu8 = tid >> 5, b = tid & 31;
          const int j2 = uu8 >> 2, uu = uu8 & 3;
          const int bt = b >> 4, c = b & 15;
          const int unit = u0 + j2*4 + uu;
          float g4[4];
          #pragma unroll
          for (int g = 0; g < 4; ++g){
            const int tr = g*4 + uu;
            const int ng = g*1024 + unit;
            g4[g] = sm.g.red[j2][bt][tr][c] + sm.g.red[j2+2][bt][tr][c]
                  + aldf(ws + DPART_F + (long long)b*4096 + ng)
                  + P.dbih[ng] + P.dbhh[ng];
          }
          const long long idx = (long long)b*1024 + unit;
          float c2 = sigf(g4[1])*ws[DC_F + idx] + sigf(g4[0])*tanhfast(g4[2]);
          ws[DC_F + idx] = c2;
          asth(wsh + DHF_H + idx, sigf(g4[3])*tanhfast(c2));
        }
      }
    }
    gbar(bar, ++ep, false);

    // ---------- PHASE B ----------
    if (bid < 32){
      // attention: pq, energies, softmax, ctx, aw/awc, alignments
      if (t < 400){
        const int b = bid;
        const int len = P.memlen[b];
        {
          union { unsigned long long u; h16 h[4]; } hu;
          hu.u = aldu64(wsh + AHF_H + (long long)cur*32768 + b*1024 + tid*4);
          #pragma unroll
          for (int j = 0; j < 4; ++j) sm.row.ah[tid*4+j] = (float)hu.h[j];
        }
        if (tid < 128) sm.row.vv[tid] = P.vw[tid];
        __syncthreads();
        {
          const int a = tid & 127, kh2 = tid >> 7;
          const float* qr  = P.qw + (long long)a*1024 + kh2*512;
          const float* ahs = &sm.row.ah[kh2*512];
          float acc = 0.f;
          for (int k = 0; k < 512; k += 4){
            float4 wq = *reinterpret_cast<const float4*>(qr + k);
            acc += wq.x*ahs[k] + wq.y*ahs[k+1] + wq.z*ahs[k+2] + wq.w*ahs[k+3];
          }
          sm.row.pqp[kh2][a] = acc;
        }
        __syncthreads();
        if (tid < 128) sm.row.pq[tid] = sm.row.pqp[0][tid] + sm.row.pqp[1][tid];
        __syncthreads();
        for (int pass = 0; pass < 2; ++pass){
          const int tt = tid + pass*256;
          if (tt < 384){
            float acc;
            if (tt < len){
              acc = 0.f;
              const unsigned long long* plp = (const unsigned long long*)
                  (wsh + PLB_H + ((long long)b*384 + tt)*128);
              for (int a0 = 0; a0 < 32; ++a0){
                union { unsigned long long u; h16 h[4]; } hu;
                hu.u = __hip_atomic_load(plp + a0, __ATOMIC_RELAXED, __HIP_MEMORY_SCOPE_AGENT);
                #pragma unroll
                for (int j = 0; j < 4; ++j)
                  acc += sm.row.vv[a0*4+j]*tanhfast(sm.row.pq[a0*4+j] + (float)hu.h[j]);
              }
            } else acc = NEGV;
            sm.row.e[tt] = acc;
          }
        }
        __syncthreads();
        float m = NEGV;
        for (int tt = tid; tt < 384; tt += 256) m = fmaxf(m, sm.row.e[tt]);
        for (int o = 32; o; o >>= 1) m = fmaxf(m, __shfl_xor(m, o, 64));
        if ((tid & 63) == 0) sm.row.red[tid >> 6] = m;
        __syncthreads();
        const float mx = fmaxf(fmaxf(sm.row.red[0], sm.row.red[1]),
                               fmaxf(sm.row.red[2], sm.row.red[3]));
        float s = 0.f;
        for (int tt = tid; tt < 384; tt += 256){
          float wvv = (tt < len) ? __expf(sm.row.e[tt] - mx) : 0.f;
          sm.row.w[tt] = wvv; s += wvv;
        }
        for (int o = 32; o; o >>= 1) s += __shfl_xor(s, o, 64);
        if ((tid & 63) == 0) sm.row.red[8 + (tid >> 6)] = s;
        __syncthreads();
        const float inv = 1.f/(sm.row.red[8]+sm.row.red[9]+sm.row.red[10]+sm.row.red[11]);
        for (int tt = tid; tt < 384; tt += 256){
          float wvv = sm.row.w[tt]*inv;
          sm.row.w[tt] = wvv;
          astf(ws + AW_F + b*384 + tt, wvv);
          float oldc = aldf(ws + AWC_F + b*384 + tt);
          astf(ws + AWC_F + b*384 + tt, oldc + wvv);
          P.out[ALIGN0 + ((long long)b*400 + t)*384 + tt] = wvv;
        }
        __syncthreads();
        {
          float a0 = 0.f, a1 = 0.f;
          const float* mrow = P.memory + (long long)b*384*512;
          for (int t4 = 0; t4 < 96; ++t4){
            float4 w4 = *reinterpret_cast<const float4*>(&sm.row.w[t4*4]);
            const float* m0 = mrow + (long long)t4*2048 + tid;
            a0 += w4.x*m0[0]   + w4.y*m0[512]  + w4.z*m0[1024] + w4.w*m0[1536];
            a1 += w4.x*m0[256] + w4.y*m0[768]  + w4.z*m0[1280] + w4.w*m0[1792];
          }
          asth(wsh + CTXF_H + b*512 + tid, a0);
          asth(wsh + CTXF_H + b*512 + 256 + tid, a1);
        }
      }
    } else if (bid < 288){
      // dec-LSTM ah/dh partial (K=2048): 16 rows/block via MFMA
      if (t < 400){
        const int n0 = (bid-32)*16;
        const int n = n0 + i16;
        f32x4 acc0 = {0,0,0,0}, acc1 = {0,0,0,0};
        const long long curO = (long long)cur*32768;
        for (int s = wv*16; s < wv*16 + 16; ++s){
          const int k0 = s*32;
          const h16* pA = (k0 < 1024) ? wsh + DWIHF_H + (long long)n*1536 + k0 + q*8
                                      : wsh + DWHHF_H + (long long)n*1024 + (k0-1024) + q*8;
          half8 A = *(const half8*)pA;
          half8 B0, B1;
          if (k0 < 1024){
            B0 = ald16(wsh + AHF_H + curO + i16*1024 + k0 + q*8);
            B1 = ald16(wsh + AHF_H + curO + (16+i16)*1024 + k0 + q*8);
          } else {
            B0 = ald16(wsh + DHF_H + i16*1024 + (k0-1024) + q*8);
            B1 = ald16(wsh + DHF_H + (16+i16)*1024 + (k0-1024) + q*8);
          }
          acc0 = MFMA16(A, B0, acc0);
          acc1 = MFMA16(A, B1, acc1);
        }
        #pragma unroll
        for (int r = 0; r < 4; ++r){
          sm.g.red[wv][0][q*4+r][i16] = acc0[r];
          sm.g.red[wv][1][q*4+r][i16] = acc1[r];
        }
        __syncthreads();
        {
          const int r16 = tid & 15, c = tid >> 4;
          #pragma unroll
          for (int bt = 0; bt < 2; ++bt){
            float v = sm.g.red[0][bt][r16][c] + sm.g.red[1][bt][r16][c]
                    + sm.g.red[2][bt][r16][c] + sm.g.red[3][bt][r16][c];
            astf(ws + DPART_F + (long long)(bt*16 + c)*4096 + n0 + r16, v);
          }
        }
      }
    } else if (bid < 320){
      // mel + gate projections for step t-1 (fp32 VALU)
      if (t >= 1){
        const int b = bid - 288;
        for (int i = tid; i < 384; i += 256){
          union { unsigned long long u; h16 h[4]; } hu;
          hu.u = (i < 256) ? aldu64(wsh + DHF_H + b*1024 + i*4)
                           : aldu64(wsh + CTXF_H + b*512 + (i-256)*4);
          #pragma unroll
          for (int j = 0; j < 4; ++j) sm.mel.hc[i*4+j] = (float)hu.h[j];
        }
        __syncthreads();
        if (tid < 160){
          const int r = tid >> 1, h2 = tid & 1;
          const float* pr  = P.pw + (long long)r*1536 + h2*768;
          const float* hcp = &sm.mel.hc[h2*768];
          float acc = 0.f;
          for (int k = 0; k < 768; k += 4){
            float4 wq = *reinterpret_cast<const float4*>(pr + k);
            acc += wq.x*hcp[k] + wq.y*hcp[k+1] + wq.z*hcp[k+2] + wq.w*hcp[k+3];
          }
          sm.mel.mp[r][h2] = acc;
        } else if (tid >= 192){
          const int l = tid - 192;
          const float* gp  = P.gw + l*24;
          const float* hcp = &sm.mel.hc[l*24];
          float acc = 0.f;
          #pragma unroll
          for (int k = 0; k < 24; ++k) acc += gp[k]*hcp[k];
          for (int o = 32; o; o >>= 1) acc += __shfl_xor(acc, o, 64);
          if (l == 0) sm.mel.gacc = acc;
        }
        __syncthreads();
        if (tid < 80)
          P.out[((long long)b*80 + tid)*400 + (t-1)] = sm.mel.mp[tid][0] + sm.mel.mp[tid][1] + P.pb[tid];
        if (tid == 80)
          P.out[GATE0 + (long long)b*400 + (t-1)] = sm.mel.gacc + P.gb[0];
      }
    }
    gbar(bar, ++ep, false);
  }
}

extern "C" void kernel_launch(void* const* d_in, const int* in_sizes, int n_in,
                              void* d_out, int out_size, void* d_ws, size_t ws_size,
                              hipStream_t stream) {
  (void)in_sizes; (void)n_in; (void)out_size; (void)ws_size;
  Params p;
  p.memory = (const float*)d_in[0];
  p.dec_in = (const float*)d_in[1];
  p.memlen = (const int*)d_in[2];
  p.w1   = (const float*)d_in[3];
  p.w2   = (const float*)d_in[4];
  p.awih = (const float*)d_in[5];
  p.awhh = (const float*)d_in[6];
  p.abih = (const float*)d_in[7];
  p.abhh = (const float*)d_in[8];
  p.qw   = (const float*)d_in[9];
  p.mw   = (const float*)d_in[10];
  p.vw   = (const float*)d_in[11];
  p.lcw  = (const float*)d_in[12];
  p.ldw  = (const float*)d_in[13];
  p.dwih = (const float*)d_in[14];
  p.dwhh = (const float*)d_in[15];
  p.dbih = (const float*)d_in[16];
  p.dbhh = (const float*)d_in[17];
  p.pw   = (const float*)d_in[18];
  p.pb   = (const float*)d_in[19];
  p.gw   = (const float*)d_in[20];
  p.gb   = (const float*)d_in[21];
  p.out  = (float*)d_out;
  p.ws   = (float*)d_ws;

  hipLaunchKernelGGL(init_kernel, dim3(1), dim3(512), 0, stream, p.ws);
  hipLaunchKernelGGL(decoder_kernel, dim3(512), dim3(256), 0, stream, p);
}